// Round 11
// baseline (4704.773 us; speedup 1.0000x reference)
//
#include <hip/hip_runtime.h>
#include <hip/hip_bf16.h>
#include <cstdint>

#define N_ROWS   65536
#define EDIM     128
#define CBSZ     256
#define NLEV     4

typedef _Float16 f16x8 __attribute__((ext_vector_type(8)));
typedef _Float16 f16x4 __attribute__((ext_vector_type(4)));
typedef float    f32x4 __attribute__((ext_vector_type(4)));

__device__ __forceinline__ void gload_lds16(const void* g, void* l) {
    __builtin_amdgcn_global_load_lds(
        (const __attribute__((address_space(1))) void*)g,
        (__attribute__((address_space(3))) void*)l, 16, 0, 0);
}

#define WAITV(n) asm volatile("s_waitcnt vmcnt(" #n ")" ::: "memory")
#define BARR()   asm volatile("s_barrier" ::: "memory")
#define PRIO(x)  __builtin_amdgcn_s_setprio(x)

// ============================================================================
// 256x256-tile counted-vmcnt MFMA GEMM (R10's verified phase discipline,
// MREP=8 per-wave tile to halve LDS bytes per MFMA: 24 frag reads / 96 MFMA).
// 512 thr = 8 waves (2 row x 4 col), per-wave 128x64 output.
// ENC=1: 3 products (Ah*Wh + Ah*Wl + Al*Wh), BK=32.
//   chunks (2 loads each): c0=Ah->As[d][0] c1=Wh->Bs[d][0] c2=Wl->Bs[d][1] c3=Al->As[d][1]
//   P0: rd ah,bh | issue c0' | 32 MFMA hh | WAITV(4|2) BARR
//   P1: rd bl    | issue c1' | 32 MFMA Ah*Wl | WAITV(4|0) BARR
//   P2: rd al    | issue c2',c3' | 32 MFMA Al*Wh | WAITV(4) BARR (skip last)
// ENC=0: single product, BK=64 (op = k-half).
//   P0: rd klo | issue c0',c1' | 32 MFMA | WAITV(4|0) BARR
//   P1: rd khi | issue c2',c3' | 32 MFMA | WAITV(4) BARR (skip last)
// All waits FIFO-derived, never drained mid-loop; every ds_read is consumed
// by an MFMA before the next barrier (no LDS read/DMA-write race).
// WRITE: 0=fp32 Cf, 1=fp16 hi->Ch + lo->Cl, 2=fp16 hi only.
// ============================================================================
template<int ENC, int WRITE, int RELU>
__global__ __launch_bounds__(512, 2)
void gemmW(const _Float16* __restrict__ Ah, const _Float16* __restrict__ Al,
           const _Float16* __restrict__ Wth, const _Float16* __restrict__ Wtl,
           const float* __restrict__ bias,
           float* __restrict__ Cf, _Float16* __restrict__ Ch, _Float16* __restrict__ Cl,
           int K, int M) {
    __shared__ __align__(16) _Float16 As[2][2][4][256][8];   // 64 KB
    __shared__ __align__(16) _Float16 Bs[2][2][4][256][8];   // 64 KB

    const int tid = threadIdx.x, w = tid >> 6, lane = tid & 63;
    const int wr = w >> 2, wc = w & 3, er = lane & 15, kq = lane >> 4;

    // bijective XCD swizzle (m204)
    const int gx   = (int)gridDim.x;
    const int nwg  = gx * (int)gridDim.y;
    const int orig = (int)blockIdx.y * gx + (int)blockIdx.x;
    const int qq = nwg >> 3, r8 = nwg & 7, xcd = orig & 7, sub = orig >> 3;
    const int wg = (xcd < r8 ? xcd * (qq + 1) : r8 * (qq + 1) + (xcd - r8) * qq) + sub;
    const long row0 = (long)(wg / gx) * 256;
    const long col0 = (long)(wg % gx) * 256;
    const long Kl = K;

    // staging: each chunk = 16KB = 2 loads/thread; row = tid&255,
    // load i covers k8 = 2i + (tid>>8); lds f16-offset = i*4096 + tid*8
    const int sr  = tid & 255;
    const int sk0 = (tid >> 8);
    const int sk1 = 2 + (tid >> 8);

    _Float16* const AsB = &As[0][0][0][0][0];
    _Float16* const BsB = &Bs[0][0][0][0][0];

    auto stA = [&](int d, int op, const _Float16* P, long ko) {
        _Float16* b = AsB + (size_t)(d * 16384 + op * 8192);
        gload_lds16(P + (row0 + sr) * Kl + ko + sk0 * 8, b + tid * 8);
        gload_lds16(P + (row0 + sr) * Kl + ko + sk1 * 8, b + 4096 + tid * 8);
    };
    auto stB = [&](int d, int op, const _Float16* P, long ko) {
        _Float16* b = BsB + (size_t)(d * 16384 + op * 8192);
        gload_lds16(P + (col0 + sr) * Kl + ko + sk0 * 8, b + tid * 8);
        gload_lds16(P + (col0 + sr) * Kl + ko + sk1 * 8, b + 4096 + tid * 8);
    };

#define RD_A8(DST, D, OP)                                                      \
    _Pragma("unroll")                                                          \
    for (int m_ = 0; m_ < 8; ++m_)                                             \
        DST[m_] = *(const f16x8*)&As[D][OP][kq][wr * 128 + m_ * 16 + er][0];
#define RD_B4(DST, D, OP)                                                      \
    _Pragma("unroll")                                                          \
    for (int n_ = 0; n_ < 4; ++n_)                                             \
        DST[n_] = *(const f16x8*)&Bs[D][OP][kq][wc * 64 + n_ * 16 + er][0];
#define MM84(B, A)                                                             \
    _Pragma("unroll")                                                          \
    for (int m_ = 0; m_ < 8; ++m_) {                                           \
        _Pragma("unroll")                                                      \
        for (int n_ = 0; n_ < 4; ++n_)                                         \
            acc[m_][n_] = __builtin_amdgcn_mfma_f32_16x16x32_f16(              \
                (B)[n_], (A)[m_], acc[m_][n_], 0, 0, 0);                       \
    }

    f32x4 acc[8][4];
#pragma unroll
    for (int m = 0; m < 8; ++m)
#pragma unroll
        for (int n = 0; n < 4; ++n) { f32x4 z = {0.f, 0.f, 0.f, 0.f}; acc[m][n] = z; }

    constexpr int BK = ENC ? 32 : 64;
    const int nt = K / BK;

    // prologue: stage tile 0 in chunk order c0,c1,c2,c3 (8 loads)
    if constexpr (ENC) {
        stA(0, 0, Ah, 0); stB(0, 0, Wth, 0);
        stB(0, 1, Wtl, 0); stA(0, 1, Al, 0);
    } else {
        stA(0, 0, Ah, 0);  stB(0, 0, Wth, 0);
        stA(0, 1, Ah, 32); stB(0, 1, Wth, 32);
    }
    WAITV(4);   // c0,c1 complete
    BARR();

    for (int kt = 0; kt < nt; ++kt) {
        const int d = kt & 1;
        const bool pre = (kt + 1 < nt);
        const long ko = (long)(kt + 1) * BK;

        if constexpr (ENC) {
            f16x8 ah[8], bh[4], bl[4], al[8];
            // ---- P0: rd ah,bh ; issue c0' ; MFMA hi*hi
            RD_A8(ah, d, 0); RD_B4(bh, d, 0);
            if (pre) stA(d ^ 1, 0, Ah, ko);
            PRIO(1); MM84(bh, ah); PRIO(0);
            if (pre) { WAITV(4); } else { WAITV(2); }
            BARR();
            // ---- P1: rd bl ; issue c1' ; MFMA Ah*Wl
            RD_B4(bl, d, 1);
            if (pre) stB(d ^ 1, 0, Wth, ko);
            PRIO(1); MM84(bl, ah); PRIO(0);
            if (pre) { WAITV(4); } else { WAITV(0); }
            BARR();
            // ---- P2: rd al ; issue c2',c3' ; MFMA Al*Wh
            RD_A8(al, d, 1);
            if (pre) { stB(d ^ 1, 1, Wtl, ko); stA(d ^ 1, 1, Al, ko); }
            PRIO(1); MM84(bh, al); PRIO(0);
            if (pre) { WAITV(4); BARR(); }
        } else {
            f16x8 a0[8], b0[4], a1[8], b1[4];
            // ---- P0: rd k-lo ; issue c0',c1' ; MFMA klo
            RD_A8(a0, d, 0); RD_B4(b0, d, 0);
            if (pre) { stA(d ^ 1, 0, Ah, ko); stB(d ^ 1, 0, Wth, ko); }
            PRIO(1); MM84(b0, a0); PRIO(0);
            if (pre) { WAITV(4); } else { WAITV(0); }
            BARR();
            // ---- P1: rd k-hi ; issue c2',c3' ; MFMA khi
            RD_A8(a1, d, 1); RD_B4(b1, d, 1);
            if (pre) { stA(d ^ 1, 1, Ah, ko + 32); stB(d ^ 1, 1, Wth, ko + 32); }
            PRIO(1); MM84(b1, a1); PRIO(0);
            if (pre) { WAITV(4); BARR(); }
        }
    }

    // epilogue: row = row0 + wr*128 + m*16 + er ; cols = col0 + wc*64 + n*16 + kq*4..+3
#pragma unroll
    for (int n = 0; n < 4; ++n) {
        const long colb = col0 + wc * 64 + n * 16 + kq * 4;
        const float4 bb = *(const float4*)&bias[colb];
#pragma unroll
        for (int m = 0; m < 8; ++m) {
            const long row = row0 + wr * 128 + m * 16 + er;
            float vx = acc[m][n][0] + bb.x;
            float vy = acc[m][n][1] + bb.y;
            float vz = acc[m][n][2] + bb.z;
            float vw = acc[m][n][3] + bb.w;
            if (RELU) {
                vx = fmaxf(vx, 0.f); vy = fmaxf(vy, 0.f);
                vz = fmaxf(vz, 0.f); vw = fmaxf(vw, 0.f);
            }
            const long idx = row * M + colb;
            if (WRITE == 0) {
                float4 v; v.x = vx; v.y = vy; v.z = vz; v.w = vw;
                *(float4*)&Cf[idx] = v;
            } else {
                f16x4 h = {(_Float16)vx, (_Float16)vy, (_Float16)vz, (_Float16)vw};
                *(f16x4*)&Ch[idx] = h;
                if (WRITE == 1) {
                    f16x4 l = {(_Float16)(vx - (float)h[0]), (_Float16)(vy - (float)h[1]),
                               (_Float16)(vz - (float)h[2]), (_Float16)(vw - (float)h[3])};
                    *(f16x4*)&Cl[idx] = l;
                }
            }
        }
    }
#undef RD_A8
#undef RD_B4
#undef MM84
}

// ============================================================================
// 256x128 ENC kernel (R10's verified gemm8p, ENC path) — used only for enc3
// (M=128). BK=32, 8 waves 4x2, 64x64/wave.
// ============================================================================
template<int ENC, int WRITE, int RELU>
__global__ __launch_bounds__(512, 2)
void gemm8p(const _Float16* __restrict__ Ah, const _Float16* __restrict__ Al,
            const _Float16* __restrict__ Wth, const _Float16* __restrict__ Wtl,
            const float* __restrict__ bias,
            float* __restrict__ Cf, _Float16* __restrict__ Ch, _Float16* __restrict__ Cl,
            int K, int M) {
    constexpr int BK = ENC ? 32 : 64;
    __shared__ __align__(16) _Float16 As[2][2][4][256][8];   // 64 KB
    __shared__ __align__(16) _Float16 Bs[2][2][4][128][8];   // 32 KB

    const int tid = threadIdx.x, w = tid >> 6, lane = tid & 63;
    const int wr = w >> 1, wc = w & 1, er = lane & 15, kq = lane >> 4;

    const int gx   = (int)gridDim.x;
    const int nwg  = gx * (int)gridDim.y;
    const int orig = (int)blockIdx.y * gx + (int)blockIdx.x;
    const int qq = nwg >> 3, r8 = nwg & 7, xcd = orig & 7, sub = orig >> 3;
    const int wg = (xcd < r8 ? xcd * (qq + 1) : r8 * (qq + 1) + (xcd - r8) * qq) + sub;
    const long row0 = (long)(wg / gx) * 256;
    const long col0 = (long)(wg % gx) * 128;
    const long Kl = K;

    const int fa0 = ((w * 2 + 0) << 9) + lane * 8;
    const int fa1 = ((w * 2 + 1) << 9) + lane * 8;
    const int fb  = (w << 9) + lane * 8;
    const int a0k8 = fa0 >> 11, a0r = (fa0 >> 3) & 255;
    const int a1k8 = fa1 >> 11, a1r = (fa1 >> 3) & 255;
    const int bk8  = fb >> 10,  br  = (fb >> 3) & 127;

    const _Float16* gA0h = Ah + (row0 + a0r) * Kl + a0k8 * 8;
    const _Float16* gA1h = Ah + (row0 + a1r) * Kl + a1k8 * 8;
    const _Float16* gB0h = Wth + (col0 + br) * Kl + bk8 * 8;
    const _Float16 *gA0l, *gA1l, *gB0l;
    if constexpr (ENC) {
        gA0l = Al  + (row0 + a0r) * Kl + a0k8 * 8;
        gA1l = Al  + (row0 + a1r) * Kl + a1k8 * 8;
        gB0l = Wtl + (col0 + br)  * Kl + bk8 * 8;
    } else {
        gA0l = gA0h + 32; gA1l = gA1h + 32; gB0l = gB0h + 32;
    }

    _Float16* const AsB = &As[0][0][0][0][0];
    _Float16* const BsB = &Bs[0][0][0][0][0];

    auto I_C0 = [&](int d, int kt) {
        const long kb = (long)kt * BK;
        gload_lds16(gA0h + kb, AsB + (size_t)d * 16384 + fa0);
        gload_lds16(gA1h + kb, AsB + (size_t)d * 16384 + fa1);
    };
    auto I_C1 = [&](int d, int kt) {
        gload_lds16(gB0h + (long)kt * BK, BsB + (size_t)d * 8192 + fb);
    };
    auto I_C2 = [&](int d, int kt) {
        const long kb = (long)kt * BK;
        if constexpr (ENC) {
            gload_lds16(gB0l + kb, BsB + (size_t)d * 8192 + 4096 + fb);
        } else {
            gload_lds16(gA0l + kb, AsB + (size_t)d * 16384 + 8192 + fa0);
            gload_lds16(gA1l + kb, AsB + (size_t)d * 16384 + 8192 + fa1);
        }
    };
    auto I_C3 = [&](int d, int kt) {
        const long kb = (long)kt * BK;
        if constexpr (ENC) {
            gload_lds16(gA0l + kb, AsB + (size_t)d * 16384 + 8192 + fa0);
            gload_lds16(gA1l + kb, AsB + (size_t)d * 16384 + 8192 + fa1);
        } else {
            gload_lds16(gB0l + kb, BsB + (size_t)d * 8192 + 4096 + fb);
        }
    };

    f32x4 acc[4][4];
#pragma unroll
    for (int m = 0; m < 4; ++m)
#pragma unroll
        for (int n = 0; n < 4; ++n) { f32x4 z = {0.f, 0.f, 0.f, 0.f}; acc[m][n] = z; }

    const int nt = K / BK;
    I_C0(0, 0); I_C1(0, 0); I_C2(0, 0); I_C3(0, 0);
    WAITV(3);
    BARR();

    for (int kt = 0; kt < nt; ++kt) {
        const int d = kt & 1;
        const bool pre = (kt + 1 < nt);
        f16x8 a0[4], b0[4], a1[4], b1[4];

        if constexpr (ENC) {
#pragma unroll
            for (int m = 0; m < 4; ++m) a0[m] = *(const f16x8*)&As[d][0][kq][wr * 64 + m * 16 + er][0];
#pragma unroll
            for (int n = 0; n < 4; ++n) b0[n] = *(const f16x8*)&Bs[d][0][kq][wc * 64 + n * 16 + er][0];
            if (pre) I_C0(d ^ 1, kt + 1);
            PRIO(1);
#pragma unroll
            for (int m = 0; m < 4; ++m)
#pragma unroll
                for (int n = 0; n < 4; ++n)
                    acc[m][n] = __builtin_amdgcn_mfma_f32_16x16x32_f16(b0[n], a0[m], acc[m][n], 0, 0, 0);
            PRIO(0);
            if (pre) { WAITV(4); } else { WAITV(2); }
            BARR();
#pragma unroll
            for (int n = 0; n < 4; ++n) b1[n] = *(const f16x8*)&Bs[d][1][kq][wc * 64 + n * 16 + er][0];
            if (pre) I_C1(d ^ 1, kt + 1);
            PRIO(1);
#pragma unroll
            for (int m = 0; m < 4; ++m)
#pragma unroll
                for (int n = 0; n < 4; ++n)
                    acc[m][n] = __builtin_amdgcn_mfma_f32_16x16x32_f16(b1[n], a0[m], acc[m][n], 0, 0, 0);
            PRIO(0);
            if (pre) { WAITV(3); } else { WAITV(0); }
            BARR();
#pragma unroll
            for (int m = 0; m < 4; ++m) a1[m] = *(const f16x8*)&As[d][1][kq][wr * 64 + m * 16 + er][0];
            if (pre) { I_C2(d ^ 1, kt + 1); I_C3(d ^ 1, kt + 1); }
            PRIO(1);
#pragma unroll
            for (int m = 0; m < 4; ++m)
#pragma unroll
                for (int n = 0; n < 4; ++n)
                    acc[m][n] = __builtin_amdgcn_mfma_f32_16x16x32_f16(b0[n], a1[m], acc[m][n], 0, 0, 0);
            PRIO(0);
            if (pre) { WAITV(3); BARR(); }
        } else {
#pragma unroll
            for (int m = 0; m < 4; ++m) a0[m] = *(const f16x8*)&As[d][0][kq][wr * 64 + m * 16 + er][0];
#pragma unroll
            for (int n = 0; n < 4; ++n) b0[n] = *(const f16x8*)&Bs[d][0][kq][wc * 64 + n * 16 + er][0];
            if (pre) I_C0(d ^ 1, kt + 1);
            PRIO(1);
#pragma unroll
            for (int m = 0; m < 4; ++m)
#pragma unroll
                for (int n = 0; n < 2; ++n)
                    acc[m][n] = __builtin_amdgcn_mfma_f32_16x16x32_f16(b0[n], a0[m], acc[m][n], 0, 0, 0);
            PRIO(0);
            if (pre) I_C1(d ^ 1, kt + 1);
            PRIO(1);
#pragma unroll
            for (int m = 0; m < 4; ++m)
#pragma unroll
                for (int n = 2; n < 4; ++n)
                    acc[m][n] = __builtin_amdgcn_mfma_f32_16x16x32_f16(b0[n], a0[m], acc[m][n], 0, 0, 0);
            PRIO(0);
            if (pre) { WAITV(3); } else { WAITV(0); }
            BARR();
#pragma unroll
            for (int m = 0; m < 4; ++m) a1[m] = *(const f16x8*)&As[d][1][kq][wr * 64 + m * 16 + er][0];
#pragma unroll
            for (int n = 0; n < 4; ++n) b1[n] = *(const f16x8*)&Bs[d][1][kq][wc * 64 + n * 16 + er][0];
            if (pre) I_C2(d ^ 1, kt + 1);
            PRIO(1);
#pragma unroll
            for (int m = 0; m < 4; ++m)
#pragma unroll
                for (int n = 0; n < 2; ++n)
                    acc[m][n] = __builtin_amdgcn_mfma_f32_16x16x32_f16(b1[n], a1[m], acc[m][n], 0, 0, 0);
            PRIO(0);
            if (pre) I_C3(d ^ 1, kt + 1);
            PRIO(1);
#pragma unroll
            for (int m = 0; m < 4; ++m)
#pragma unroll
                for (int n = 2; n < 4; ++n)
                    acc[m][n] = __builtin_amdgcn_mfma_f32_16x16x32_f16(b1[n], a1[m], acc[m][n], 0, 0, 0);
            PRIO(0);
            if (pre) { WAITV(3); BARR(); }
        }
    }

#pragma unroll
    for (int n = 0; n < 4; ++n) {
        const long colb = col0 + wc * 64 + n * 16 + kq * 4;
        const float4 bb = *(const float4*)&bias[colb];
#pragma unroll
        for (int m = 0; m < 4; ++m) {
            const long row = row0 + wr * 64 + m * 16 + er;
            float vx = acc[m][n][0] + bb.x;
            float vy = acc[m][n][1] + bb.y;
            float vz = acc[m][n][2] + bb.z;
            float vw = acc[m][n][3] + bb.w;
            if (RELU) {
                vx = fmaxf(vx, 0.f); vy = fmaxf(vy, 0.f);
                vz = fmaxf(vz, 0.f); vw = fmaxf(vw, 0.f);
            }
            const long idx = row * M + colb;
            if (WRITE == 0) {
                float4 v; v.x = vx; v.y = vy; v.z = vz; v.w = vw;
                *(float4*)&Cf[idx] = v;
            } else {
                f16x4 h = {(_Float16)vx, (_Float16)vy, (_Float16)vz, (_Float16)vw};
                *(f16x4*)&Ch[idx] = h;
                if (WRITE == 1) {
                    f16x4 l = {(_Float16)(vx - (float)h[0]), (_Float16)(vy - (float)h[1]),
                               (_Float16)(vz - (float)h[2]), (_Float16)(vw - (float)h[3])};
                    *(f16x4*)&Cl[idx] = l;
                }
            }
        }
    }
}

// ============================================================================
__global__ __launch_bounds__(256)
void splitWT(const float* __restrict__ W, _Float16* __restrict__ th,
             _Float16* __restrict__ tl, int K, int M) {
    long i = (long)blockIdx.x * 256 + threadIdx.x;
    if (i >= (long)K * M) return;
    int m = (int)(i / K), k = (int)(i % K);
    float v = W[(long)k * M + m];
    _Float16 h = (_Float16)v;
    th[i] = h;
    tl[i] = (_Float16)(v - (float)h);
}

__global__ __launch_bounds__(256)
void split_pair(const float* __restrict__ s, _Float16* __restrict__ h,
                _Float16* __restrict__ l, long n4) {
    long i = (long)blockIdx.x * 256 + threadIdx.x;
    if (i >= n4) return;
    float4 v = ((const float4*)s)[i];
    float a[4] = {v.x, v.y, v.z, v.w};
    f16x4 hv, lv;
#pragma unroll
    for (int j = 0; j < 4; ++j) {
        _Float16 hh = (_Float16)a[j];
        hv[j] = hh;
        lv[j] = (_Float16)(a[j] - (float)hh);
    }
    *(f16x4*)&h[i * 4] = hv;
    *(f16x4*)&l[i * 4] = lv;
}

// ============================================================================
// VQ level (fp32, exact argmin, first-min tie-break).
// ============================================================================
__global__ __launch_bounds__(512)
void vq_level(const float* __restrict__ resin, float* __restrict__ resout,
              const float* __restrict__ codebooks, int level,
              float* __restrict__ loss_part, float* __restrict__ idxf) {
    __shared__ float ct[EDIM][CBSZ + 4];
    __shared__ float cnorm[CBSZ];
    __shared__ float res_row[8][2][EDIM];

    const float* cb = codebooks + (long)level * CBSZ * EDIM;

    for (int e = threadIdx.x; e < CBSZ * EDIM; e += 512) {
        int j = e >> 7, d = e & 127;
        ct[d][j] = cb[e];
    }
    __syncthreads();
    for (int j = threadIdx.x; j < CBSZ; j += 512) {
        float s = 0.f;
        for (int d = 0; d < EDIM; ++d) s = fmaf(ct[d][j], ct[d][j], s);
        cnorm[j] = s;
    }
    __syncthreads();

    const int w    = threadIdx.x >> 6;
    const int lane = threadIdx.x & 63;
    const int wg   = blockIdx.x * 8 + w;
    const int jb   = lane * 4;
    float local_loss = 0.f;

    for (int p = 0; p < 16; ++p) {
        const long rA = (long)wg + (long)(2 * p) * 2048;
        const long rB = rA + 2048;

        float2 rvA = *reinterpret_cast<const float2*>(&resin[rA * EDIM + 2 * lane]);
        float2 rvB = *reinterpret_cast<const float2*>(&resin[rB * EDIM + 2 * lane]);
        res_row[w][0][2 * lane] = rvA.x; res_row[w][0][2 * lane + 1] = rvA.y;
        res_row[w][1][2 * lane] = rvB.x; res_row[w][1][2 * lane + 1] = rvB.y;

        float rrA = rvA.x * rvA.x + rvA.y * rvA.y;
        float rrB = rvB.x * rvB.x + rvB.y * rvB.y;
#pragma unroll
        for (int off = 32; off; off >>= 1) {
            rrA += __shfl_xor(rrA, off);
            rrB += __shfl_xor(rrB, off);
        }

        float dA0 = 0, dA1 = 0, dA2 = 0, dA3 = 0;
        float dB0 = 0, dB1 = 0, dB2 = 0, dB3 = 0;
        for (int d = 0; d < EDIM; d += 4) {
            float4 ra = *reinterpret_cast<const float4*>(&res_row[w][0][d]);
            float4 rb = *reinterpret_cast<const float4*>(&res_row[w][1][d]);
            const float* rap = &ra.x;
            const float* rbp = &rb.x;
#pragma unroll
            for (int dd = 0; dd < 4; ++dd) {
                float4 cv = *reinterpret_cast<const float4*>(&ct[d + dd][jb]);
                float rax = rap[dd], rbx = rbp[dd];
                dA0 = fmaf(rax, cv.x, dA0); dA1 = fmaf(rax, cv.y, dA1);
                dA2 = fmaf(rax, cv.z, dA2); dA3 = fmaf(rax, cv.w, dA3);
                dB0 = fmaf(rbx, cv.x, dB0); dB1 = fmaf(rbx, cv.y, dB1);
                dB2 = fmaf(rbx, cv.z, dB2); dB3 = fmaf(rbx, cv.w, dB3);
            }
        }

        float4 nv = *reinterpret_cast<const float4*>(&cnorm[jb]);
        float vA0 = fmaf(-2.f, dA0, rrA) + nv.x;
        float vA1 = fmaf(-2.f, dA1, rrA) + nv.y;
        float vA2 = fmaf(-2.f, dA2, rrA) + nv.z;
        float vA3 = fmaf(-2.f, dA3, rrA) + nv.w;
        float vB0 = fmaf(-2.f, dB0, rrB) + nv.x;
        float vB1 = fmaf(-2.f, dB1, rrB) + nv.y;
        float vB2 = fmaf(-2.f, dB2, rrB) + nv.z;
        float vB3 = fmaf(-2.f, dB3, rrB) + nv.w;

        float bvA = vA0; int biA = jb;
        if (vA1 < bvA) { bvA = vA1; biA = jb + 1; }
        if (vA2 < bvA) { bvA = vA2; biA = jb + 2; }
        if (vA3 < bvA) { bvA = vA3; biA = jb + 3; }
        float bvB = vB0; int biB = jb;
        if (vB1 < bvB) { bvB = vB1; biB = jb + 1; }
        if (vB2 < bvB) { bvB = vB2; biB = jb + 2; }
        if (vB3 < bvB) { bvB = vB3; biB = jb + 3; }

#pragma unroll
        for (int off = 32; off; off >>= 1) {
            float ovA = __shfl_xor(bvA, off); int oiA = __shfl_xor(biA, off);
            if (ovA < bvA || (ovA == bvA && oiA < biA)) { bvA = ovA; biA = oiA; }
            float ovB = __shfl_xor(bvB, off); int oiB = __shfl_xor(biB, off);
            if (ovB < bvB || (ovB == bvB && oiB < biB)) { bvB = ovB; biB = oiB; }
        }

        float2 qa = *reinterpret_cast<const float2*>(&cb[(long)biA * EDIM + 2 * lane]);
        float2 qb = *reinterpret_cast<const float2*>(&cb[(long)biB * EDIM + 2 * lane]);
        float2 nrA; nrA.x = rvA.x - qa.x; nrA.y = rvA.y - qa.y;
        float2 nrB; nrB.x = rvB.x - qb.x; nrB.y = rvB.y - qb.y;
        *reinterpret_cast<float2*>(&resout[rA * EDIM + 2 * lane]) = nrA;
        *reinterpret_cast<float2*>(&resout[rB * EDIM + 2 * lane]) = nrB;

        if (lane == 0) {
            local_loss += bvA + bvB;
            idxf[rA * NLEV + level] = (float)biA;
            idxf[rB * NLEV + level] = (float)biB;
        }
    }
    if (lane == 0) loss_part[(long)level * 2048 + wg] = local_loss;
}

__global__ __launch_bounds__(256)
void finalize_xq(const float* __restrict__ z, const float* __restrict__ res,
                 _Float16* __restrict__ xqh, float* __restrict__ xq_out) {
    long i = (long)blockIdx.x * 256 + threadIdx.x;
    float4 zv = ((const float4*)z)[i];
    float4 rv = ((const float4*)res)[i];
    float vx = zv.x - rv.x, vy = zv.y - rv.y, vz = zv.z - rv.z, vw = zv.w - rv.w;
    f16x4 hv = {(_Float16)vx, (_Float16)vy, (_Float16)vz, (_Float16)vw};
    *(f16x4*)&xqh[i * 4] = hv;
    long b = i * 4;
    xq_out[b + 0] = vx; xq_out[b + 1] = vy;
    xq_out[b + 2] = vz; xq_out[b + 3] = vw;
}

__global__ __launch_bounds__(256)
void loss_final(const float* __restrict__ part, float* __restrict__ out) {
    __shared__ float s[256];
    float acc = 0.f;
    for (int i = threadIdx.x; i < NLEV * 2048; i += 256) acc += part[i];
    s[threadIdx.x] = acc;
    __syncthreads();
    for (int st = 128; st; st >>= 1) {
        if (threadIdx.x < st) s[threadIdx.x] += s[threadIdx.x + st];
        __syncthreads();
    }
    if (threadIdx.x == 0)
        out[0] = s[0] * (1.001f / (4.0f * (float)N_ROWS * (float)EDIM));
}

// ============================================================================
extern "C" void kernel_launch(void* const* d_in, const int* in_sizes, int n_in,
                              void* d_out, int out_size, void* d_ws, size_t ws_size,
                              hipStream_t stream) {
    const float* x  = (const float*)d_in[0];
    const float* ew[4] = {(const float*)d_in[1], (const float*)d_in[3],
                          (const float*)d_in[5], (const float*)d_in[7]};
    const float* eb[4] = {(const float*)d_in[2], (const float*)d_in[4],
                          (const float*)d_in[6], (const float*)d_in[8]};
    const float* dw[4] = {(const float*)d_in[9],  (const float*)d_in[11],
                          (const float*)d_in[13], (const float*)d_in[15]};
    const float* db[4] = {(const float*)d_in[10], (const float*)d_in[12],
                          (const float*)d_in[14], (const float*)d_in[16]};
    const float* cbs = (const float*)d_in[17];

    float* out = (float*)d_out;
    const long LOSS_OFF = (long)N_ROWS * 768;
    const long IDX_OFF  = LOSS_OFF + 1;
    const long XQ_OFF   = IDX_OFF + (long)N_ROWS * 4;

    const int encK[4] = {768, 2048, 1024, 512}, encM[4] = {2048, 1024, 512, 128};
    const int decK[4] = {128, 512, 1024, 2048}, decM[4] = {512, 1024, 2048, 768};

    float* wsf = (float*)d_ws;
    long o32 = 0;
    float* zf    = wsf + o32; o32 += (long)N_ROWS * EDIM;
    float* res   = wsf + o32; o32 += (long)N_ROWS * EDIM;
    float* lossp = wsf + o32; o32 += NLEV * 2048;
    o32 = (o32 + 7) & ~7L;

    _Float16* wsh = (_Float16*)(wsf + o32);
    long oh = 0;
    _Float16* xqh = wsh + oh; oh += (long)N_ROWS * EDIM;
    _Float16 *ewh[4], *ewl[4], *dwh[4], *dwl[4];
    for (int j = 0; j < 4; ++j) {
        long n = (long)encK[j] * encM[j];
        ewh[j] = wsh + oh; oh += n;
        ewl[j] = wsh + oh; oh += n;
    }
    for (int j = 0; j < 4; ++j) {
        long n = (long)decK[j] * decM[j];
        dwh[j] = wsh + oh; oh += n;
        dwl[j] = wsh + oh; oh += n;
    }
    _Float16* a0h = wsh + oh; oh += (long)N_ROWS * 512;
    _Float16* a0l = wsh + oh; oh += (long)N_ROWS * 512;
    const long fixed_h = oh;

    long R = 32768;
    while (R > 2048) {
        size_t need = (size_t)o32 * 4 + (size_t)(fixed_h + R * (1536 + 4096 + 2048)) * 2;
        if (need <= ws_size) break;
        R >>= 1;
    }
    _Float16* xh  = wsh + oh; oh += R * 768;
    _Float16* xl  = wsh + oh; oh += R * 768;
    _Float16* a2h = wsh + oh; oh += R * 2048;
    _Float16* a2l = wsh + oh; oh += R * 2048;
    _Float16* a1h = wsh + oh; oh += R * 1024;
    _Float16* a1l = wsh + oh; oh += R * 1024;

    for (int j = 0; j < 4; ++j) {
        long n = (long)encK[j] * encM[j];
        splitWT<<<dim3((unsigned)((n + 255) / 256)), 256, 0, stream>>>(ew[j], ewh[j], ewl[j], encK[j], encM[j]);
        n = (long)decK[j] * decM[j];
        splitWT<<<dim3((unsigned)((n + 255) / 256)), 256, 0, stream>>>(dw[j], dwh[j], dwl[j], decK[j], decM[j]);
    }

    const int nchunks = N_ROWS / (int)R;
    const unsigned gy = (unsigned)(R / 256);
    const dim3 blk(512);

    // ---- encoder layers 0-2 (256^2 MREP=8 kernel), layer 3 (M=128) legacy ----
    for (int c = 0; c < nchunks; ++c) {
        split_pair<<<dim3((unsigned)((R * 768 / 4 + 255) / 256)), 256, 0, stream>>>(
            x + (long)c * R * 768, xh, xl, R * 768 / 4);
        gemmW<1,1,1><<<dim3(8, gy), blk, 0, stream>>>(xh,  xl,  ewh[0], ewl[0], eb[0],
                                                      nullptr, a2h, a2l, 768,  2048);
        gemmW<1,1,1><<<dim3(4, gy), blk, 0, stream>>>(a2h, a2l, ewh[1], ewl[1], eb[1],
                                                      nullptr, a1h, a1l, 2048, 1024);
        gemmW<1,1,1><<<dim3(2, gy), blk, 0, stream>>>(a1h, a1l, ewh[2], ewl[2], eb[2],
                                                      nullptr, a0h + (long)c * R * 512,
                                                      a0l + (long)c * R * 512, 1024, 512);
    }
    gemm8p<1,0,0><<<dim3(1, N_ROWS / 256), blk, 0, stream>>>(a0h, a0l, ewh[3], ewl[3], eb[3],
                                                             zf, nullptr, nullptr, 512, 128);

    // ---- residual VQ (fp32, exact) ----
    for (int l = 0; l < NLEV; ++l)
        vq_level<<<256, 512, 0, stream>>>(l == 0 ? zf : res, res, cbs, l, lossp, out + IDX_OFF);

    finalize_xq<<<(N_ROWS * EDIM / 4) / 256, 256, 0, stream>>>(zf, res, xqh, out + XQ_OFF);
    loss_final<<<1, 256, 0, stream>>>(lossp, out + LOSS_OFF);

    // ---- decoder (256^2 MREP=8 kernel) ----
    for (int c = 0; c < nchunks; ++c) {
        gemmW<0,2,1><<<dim3(2, gy), blk, 0, stream>>>(xqh + (long)c * R * EDIM, nullptr,
                                                      dwh[0], nullptr, db[0],
                                                      nullptr, a0h, nullptr, 128,  512);
        gemmW<0,2,1><<<dim3(4, gy), blk, 0, stream>>>(a0h, nullptr, dwh[1], nullptr, db[1],
                                                      nullptr, a1h, nullptr, 512,  1024);
        gemmW<0,2,1><<<dim3(8, gy), blk, 0, stream>>>(a1h, nullptr, dwh[2], nullptr, db[2],
                                                      nullptr, a2h, nullptr, 1024, 2048);
        gemmW<0,0,0><<<dim3(3, gy), blk, 0, stream>>>(a2h, nullptr, dwh[3], nullptr, db[3],
                                                      out + (long)c * R * 768, nullptr, nullptr, 2048, 768);
    }
}

// Round 12
// 4249.141 us; speedup vs baseline: 1.1072x; 1.1072x over previous
//
#include <hip/hip_runtime.h>
#include <hip/hip_bf16.h>
#include <cstdint>

#define N_ROWS   65536
#define EDIM     128
#define CBSZ     256
#define NLEV     4

typedef _Float16 f16x8 __attribute__((ext_vector_type(8)));
typedef _Float16 f16x4 __attribute__((ext_vector_type(4)));
typedef float    f32x4 __attribute__((ext_vector_type(4)));

__device__ __forceinline__ void gload_lds16(const void* g, void* l) {
    __builtin_amdgcn_global_load_lds(
        (const __attribute__((address_space(1))) void*)g,
        (__attribute__((address_space(3))) void*)l, 16, 0, 0);
}

#define WAITV(n) asm volatile("s_waitcnt vmcnt(" #n ")" ::: "memory")
#define BARR()   asm volatile("s_barrier" ::: "memory")
#define PRIO(x)  __builtin_amdgcn_s_setprio(x)

// ============================================================================
// Counted-vmcnt MFMA GEMM, tile 128x128, 256 threads (4 waves 2x2, 64x64/wave),
// 64KB LDS -> 2 blocks/CU: cross-block overlap hides per-block barrier drains
// (m97/m114 mechanism) while keeping R4's verified phase/vmcnt discipline.
//
// ENC=1 (BK=32, 3 products = fp32-like fp16 split):
//   chunks (2 loads each): c0=Ah->As[d][0] c1=Wh->Bs[d][0] c2=Wl->Bs[d][1] c3=Al->As[d][1]
//   P0: rd ah,bh | issue c0' | 16 MFMA hh    | WAITV(4|2) BARR
//   P1: rd bl    | issue c1' | 16 MFMA Ah*Wl | WAITV(4|0) BARR
//   P2: rd al    | issue c2',c3' | 16 MFMA Al*Wh | WAITV(4) BARR (skip last)
// ENC=0 (BK=64, single product; op = k-half):
//   P0: rd klo | issue c0',c1' | 16 MFMA | WAITV(4|0) BARR
//   P1: rd khi | issue c2',c3' | 16 MFMA | WAITV(4) BARR (skip last)
// FIFO-derived waits (2-load chunks -> uniform 4), never drained mid-loop.
// Every ds_read is consumed by an MFMA before the next barrier -> no LDS
// read / DMA-write race (the R4-proven safety argument).
// WRITE: 0=fp32 Cf, 1=fp16 hi->Ch + lo->Cl, 2=fp16 hi only.
// ============================================================================
template<int ENC, int WRITE, int RELU>
__global__ __launch_bounds__(256, 2)
void gemmQ(const _Float16* __restrict__ Ah, const _Float16* __restrict__ Al,
           const _Float16* __restrict__ Wth, const _Float16* __restrict__ Wtl,
           const float* __restrict__ bias,
           float* __restrict__ Cf, _Float16* __restrict__ Ch, _Float16* __restrict__ Cl,
           int K, int M) {
    constexpr int BK = ENC ? 32 : 64;
    __shared__ __align__(16) _Float16 As[2][2][4][128][8];   // 32 KB
    __shared__ __align__(16) _Float16 Bs[2][2][4][128][8];   // 32 KB

    const int tid = threadIdx.x, w = tid >> 6, lane = tid & 63;
    const int wr = w >> 1, wc = w & 1, er = lane & 15, kq = lane >> 4;

    // bijective XCD swizzle (m204): consecutive wgid within an XCD share A-panel
    const int gx   = (int)gridDim.x;
    const int nwg  = gx * (int)gridDim.y;
    const int orig = (int)blockIdx.y * gx + (int)blockIdx.x;
    const int qq = nwg >> 3, r8 = nwg & 7, xcd = orig & 7, sub = orig >> 3;
    const int wg = (xcd < r8 ? xcd * (qq + 1) : r8 * (qq + 1) + (xcd - r8) * qq) + sub;
    const long row0 = (long)(wg / gx) * 128;
    const long col0 = (long)(wg % gx) * 128;
    const long Kl = K;

    // staging: chunk = 8KB = 2 loads/thread of 16B.
    // load i (i=0,1): k8 = 2*i + (tid>>7), row/col = tid&127,
    // lds f16-offset = i*2048 + tid*8 within the [4][128][8] chunk block.
    const int sr  = tid & 127;
    const int sk0 = tid >> 7;        // 0..1
    const int sk1 = 2 + (tid >> 7);  // 2..3

    _Float16* const AsB = &As[0][0][0][0][0];
    _Float16* const BsB = &Bs[0][0][0][0][0];

    auto stA = [&](int d, int op, const _Float16* P, long ko) {
        _Float16* b = AsB + (size_t)(d * 8192 + op * 4096);
        gload_lds16(P + (row0 + sr) * Kl + ko + sk0 * 8, b + tid * 8);
        gload_lds16(P + (row0 + sr) * Kl + ko + sk1 * 8, b + 2048 + tid * 8);
    };
    auto stB = [&](int d, int op, const _Float16* P, long ko) {
        _Float16* b = BsB + (size_t)(d * 8192 + op * 4096);
        gload_lds16(P + (col0 + sr) * Kl + ko + sk0 * 8, b + tid * 8);
        gload_lds16(P + (col0 + sr) * Kl + ko + sk1 * 8, b + 2048 + tid * 8);
    };

#define RD_A4(DST, D, OP)                                                      \
    _Pragma("unroll")                                                          \
    for (int m_ = 0; m_ < 4; ++m_)                                             \
        DST[m_] = *(const f16x8*)&As[D][OP][kq][wr * 64 + m_ * 16 + er][0];
#define RD_B4(DST, D, OP)                                                      \
    _Pragma("unroll")                                                          \
    for (int n_ = 0; n_ < 4; ++n_)                                             \
        DST[n_] = *(const f16x8*)&Bs[D][OP][kq][wc * 64 + n_ * 16 + er][0];
#define MM44(B, A)                                                             \
    _Pragma("unroll")                                                          \
    for (int m_ = 0; m_ < 4; ++m_) {                                           \
        _Pragma("unroll")                                                      \
        for (int n_ = 0; n_ < 4; ++n_)                                         \
            acc[m_][n_] = __builtin_amdgcn_mfma_f32_16x16x32_f16(              \
                (B)[n_], (A)[m_], acc[m_][n_], 0, 0, 0);                       \
    }

    f32x4 acc[4][4];
#pragma unroll
    for (int m = 0; m < 4; ++m)
#pragma unroll
        for (int n = 0; n < 4; ++n) { f32x4 z = {0.f, 0.f, 0.f, 0.f}; acc[m][n] = z; }

    const int nt = K / BK;

    // prologue: stage tile 0 in chunk order c0,c1,c2,c3 (8 loads); certify c0,c1
    if constexpr (ENC) {
        stA(0, 0, Ah, 0); stB(0, 0, Wth, 0);
        stB(0, 1, Wtl, 0); stA(0, 1, Al, 0);
    } else {
        stA(0, 0, Ah, 0);  stB(0, 0, Wth, 0);
        stA(0, 1, Ah, 32); stB(0, 1, Wth, 32);
    }
    WAITV(4);
    BARR();

    for (int kt = 0; kt < nt; ++kt) {
        const int d = kt & 1;
        const bool pre = (kt + 1 < nt);
        const long ko = (long)(kt + 1) * BK;

        if constexpr (ENC) {
            f16x8 ah[4], bh[4], bl[4], al[4];
            // ---- P0: rd ah,bh ; issue c0' ; MFMA hi*hi
            RD_A4(ah, d, 0); RD_B4(bh, d, 0);
            if (pre) stA(d ^ 1, 0, Ah, ko);
            PRIO(1); MM44(bh, ah); PRIO(0);
            if (pre) { WAITV(4); } else { WAITV(2); }
            BARR();
            // ---- P1: rd bl ; issue c1' ; MFMA Ah*Wl
            RD_B4(bl, d, 1);
            if (pre) stB(d ^ 1, 0, Wth, ko);
            PRIO(1); MM44(bl, ah); PRIO(0);
            if (pre) { WAITV(4); } else { WAITV(0); }
            BARR();
            // ---- P2: rd al ; issue c2',c3' ; MFMA Al*Wh
            RD_A4(al, d, 1);
            if (pre) { stB(d ^ 1, 1, Wtl, ko); stA(d ^ 1, 1, Al, ko); }
            PRIO(1); MM44(bh, al); PRIO(0);
            if (pre) { WAITV(4); BARR(); }
        } else {
            f16x8 a0[4], b0[4], a1[4], b1[4];
            // ---- P0: rd k-lo ; issue c0',c1' ; MFMA klo
            RD_A4(a0, d, 0); RD_B4(b0, d, 0);
            if (pre) { stA(d ^ 1, 0, Ah, ko); stB(d ^ 1, 0, Wth, ko); }
            PRIO(1); MM44(b0, a0); PRIO(0);
            if (pre) { WAITV(4); } else { WAITV(0); }
            BARR();
            // ---- P1: rd k-hi ; issue c2',c3' ; MFMA khi
            RD_A4(a1, d, 1); RD_B4(b1, d, 1);
            if (pre) { stA(d ^ 1, 1, Ah, ko + 32); stB(d ^ 1, 1, Wth, ko + 32); }
            PRIO(1); MM44(b1, a1); PRIO(0);
            if (pre) { WAITV(4); BARR(); }
        }
    }

    // epilogue: row = row0 + wr*64 + m*16 + er ; cols = col0 + wc*64 + n*16 + kq*4..+3
#pragma unroll
    for (int n = 0; n < 4; ++n) {
        const long colb = col0 + wc * 64 + n * 16 + kq * 4;
        const float4 bb = *(const float4*)&bias[colb];
#pragma unroll
        for (int m = 0; m < 4; ++m) {
            const long row = row0 + wr * 64 + m * 16 + er;
            float vx = acc[m][n][0] + bb.x;
            float vy = acc[m][n][1] + bb.y;
            float vz = acc[m][n][2] + bb.z;
            float vw = acc[m][n][3] + bb.w;
            if (RELU) {
                vx = fmaxf(vx, 0.f); vy = fmaxf(vy, 0.f);
                vz = fmaxf(vz, 0.f); vw = fmaxf(vw, 0.f);
            }
            const long idx = row * M + colb;
            if (WRITE == 0) {
                float4 v; v.x = vx; v.y = vy; v.z = vz; v.w = vw;
                *(float4*)&Cf[idx] = v;
            } else {
                f16x4 h = {(_Float16)vx, (_Float16)vy, (_Float16)vz, (_Float16)vw};
                *(f16x4*)&Ch[idx] = h;
                if (WRITE == 1) {
                    f16x4 l = {(_Float16)(vx - (float)h[0]), (_Float16)(vy - (float)h[1]),
                               (_Float16)(vz - (float)h[2]), (_Float16)(vw - (float)h[3])};
                    *(f16x4*)&Cl[idx] = l;
                }
            }
        }
    }
#undef RD_A4
#undef RD_B4
#undef MM44
}

// ============================================================================
__global__ __launch_bounds__(256)
void splitWT(const float* __restrict__ W, _Float16* __restrict__ th,
             _Float16* __restrict__ tl, int K, int M) {
    long i = (long)blockIdx.x * 256 + threadIdx.x;
    if (i >= (long)K * M) return;
    int m = (int)(i / K), k = (int)(i % K);
    float v = W[(long)k * M + m];
    _Float16 h = (_Float16)v;
    th[i] = h;
    tl[i] = (_Float16)(v - (float)h);
}

__global__ __launch_bounds__(256)
void split_pair(const float* __restrict__ s, _Float16* __restrict__ h,
                _Float16* __restrict__ l, long n4) {
    long i = (long)blockIdx.x * 256 + threadIdx.x;
    if (i >= n4) return;
    float4 v = ((const float4*)s)[i];
    float a[4] = {v.x, v.y, v.z, v.w};
    f16x4 hv, lv;
#pragma unroll
    for (int j = 0; j < 4; ++j) {
        _Float16 hh = (_Float16)a[j];
        hv[j] = hh;
        lv[j] = (_Float16)(a[j] - (float)hh);
    }
    *(f16x4*)&h[i * 4] = hv;
    *(f16x4*)&l[i * 4] = lv;
}

// ============================================================================
// VQ level (fp32, exact argmin, first-min tie-break).
// ============================================================================
__global__ __launch_bounds__(512)
void vq_level(const float* __restrict__ resin, float* __restrict__ resout,
              const float* __restrict__ codebooks, int level,
              float* __restrict__ loss_part, float* __restrict__ idxf) {
    __shared__ float ct[EDIM][CBSZ + 4];
    __shared__ float cnorm[CBSZ];
    __shared__ float res_row[8][2][EDIM];

    const float* cb = codebooks + (long)level * CBSZ * EDIM;

    for (int e = threadIdx.x; e < CBSZ * EDIM; e += 512) {
        int j = e >> 7, d = e & 127;
        ct[d][j] = cb[e];
    }
    __syncthreads();
    for (int j = threadIdx.x; j < CBSZ; j += 512) {
        float s = 0.f;
        for (int d = 0; d < EDIM; ++d) s = fmaf(ct[d][j], ct[d][j], s);
        cnorm[j] = s;
    }
    __syncthreads();

    const int w    = threadIdx.x >> 6;
    const int lane = threadIdx.x & 63;
    const int wg   = blockIdx.x * 8 + w;
    const int jb   = lane * 4;
    float local_loss = 0.f;

    for (int p = 0; p < 16; ++p) {
        const long rA = (long)wg + (long)(2 * p) * 2048;
        const long rB = rA + 2048;

        float2 rvA = *reinterpret_cast<const float2*>(&resin[rA * EDIM + 2 * lane]);
        float2 rvB = *reinterpret_cast<const float2*>(&resin[rB * EDIM + 2 * lane]);
        res_row[w][0][2 * lane] = rvA.x; res_row[w][0][2 * lane + 1] = rvA.y;
        res_row[w][1][2 * lane] = rvB.x; res_row[w][1][2 * lane + 1] = rvB.y;

        float rrA = rvA.x * rvA.x + rvA.y * rvA.y;
        float rrB = rvB.x * rvB.x + rvB.y * rvB.y;
#pragma unroll
        for (int off = 32; off; off >>= 1) {
            rrA += __shfl_xor(rrA, off);
            rrB += __shfl_xor(rrB, off);
        }

        float dA0 = 0, dA1 = 0, dA2 = 0, dA3 = 0;
        float dB0 = 0, dB1 = 0, dB2 = 0, dB3 = 0;
        for (int d = 0; d < EDIM; d += 4) {
            float4 ra = *reinterpret_cast<const float4*>(&res_row[w][0][d]);
            float4 rb = *reinterpret_cast<const float4*>(&res_row[w][1][d]);
            const float* rap = &ra.x;
            const float* rbp = &rb.x;
#pragma unroll
            for (int dd = 0; dd < 4; ++dd) {
                float4 cv = *reinterpret_cast<const float4*>(&ct[d + dd][jb]);
                float rax = rap[dd], rbx = rbp[dd];
                dA0 = fmaf(rax, cv.x, dA0); dA1 = fmaf(rax, cv.y, dA1);
                dA2 = fmaf(rax, cv.z, dA2); dA3 = fmaf(rax, cv.w, dA3);
                dB0 = fmaf(rbx, cv.x, dB0); dB1 = fmaf(rbx, cv.y, dB1);
                dB2 = fmaf(rbx, cv.z, dB2); dB3 = fmaf(rbx, cv.w, dB3);
            }
        }

        float4 nv = *reinterpret_cast<const float4*>(&cnorm[jb]);
        float vA0 = fmaf(-2.f, dA0, rrA) + nv.x;
        float vA1 = fmaf(-2.f, dA1, rrA) + nv.y;
        float vA2 = fmaf(-2.f, dA2, rrA) + nv.z;
        float vA3 = fmaf(-2.f, dA3, rrA) + nv.w;
        float vB0 = fmaf(-2.f, dB0, rrB) + nv.x;
        float vB1 = fmaf(-2.f, dB1, rrB) + nv.y;
        float vB2 = fmaf(-2.f, dB2, rrB) + nv.z;
        float vB3 = fmaf(-2.f, dB3, rrB) + nv.w;

        float bvA = vA0; int biA = jb;
        if (vA1 < bvA) { bvA = vA1; biA = jb + 1; }
        if (vA2 < bvA) { bvA = vA2; biA = jb + 2; }
        if (vA3 < bvA) { bvA = vA3; biA = jb + 3; }
        float bvB = vB0; int biB = jb;
        if (vB1 < bvB) { bvB = vB1; biB = jb + 1; }
        if (vB2 < bvB) { bvB = vB2; biB = jb + 2; }
        if (vB3 < bvB) { bvB = vB3; biB = jb + 3; }

#pragma unroll
        for (int off = 32; off; off >>= 1) {
            float ovA = __shfl_xor(bvA, off); int oiA = __shfl_xor(biA, off);
            if (ovA < bvA || (ovA == bvA && oiA < biA)) { bvA = ovA; biA = oiA; }
            float ovB = __shfl_xor(bvB, off); int oiB = __shfl_xor(biB, off);
            if (ovB < bvB || (ovB == bvB && oiB < biB)) { bvB = ovB; biB = oiB; }
        }

        float2 qa = *reinterpret_cast<const float2*>(&cb[(long)biA * EDIM + 2 * lane]);
        float2 qb = *reinterpret_cast<const float2*>(&cb[(long)biB * EDIM + 2 * lane]);
        float2 nrA; nrA.x = rvA.x - qa.x; nrA.y = rvA.y - qa.y;
        float2 nrB; nrB.x = rvB.x - qb.x; nrB.y = rvB.y - qb.y;
        *reinterpret_cast<float2*>(&resout[rA * EDIM + 2 * lane]) = nrA;
        *reinterpret_cast<float2*>(&resout[rB * EDIM + 2 * lane]) = nrB;

        if (lane == 0) {
            local_loss += bvA + bvB;
            idxf[rA * NLEV + level] = (float)biA;
            idxf[rB * NLEV + level] = (float)biB;
        }
    }
    if (lane == 0) loss_part[(long)level * 2048 + wg] = local_loss;
}

__global__ __launch_bounds__(256)
void finalize_xq(const float* __restrict__ z, const float* __restrict__ res,
                 _Float16* __restrict__ xqh, float* __restrict__ xq_out) {
    long i = (long)blockIdx.x * 256 + threadIdx.x;
    float4 zv = ((const float4*)z)[i];
    float4 rv = ((const float4*)res)[i];
    float vx = zv.x - rv.x, vy = zv.y - rv.y, vz = zv.z - rv.z, vw = zv.w - rv.w;
    f16x4 hv = {(_Float16)vx, (_Float16)vy, (_Float16)vz, (_Float16)vw};
    *(f16x4*)&xqh[i * 4] = hv;
    long b = i * 4;
    xq_out[b + 0] = vx; xq_out[b + 1] = vy;
    xq_out[b + 2] = vz; xq_out[b + 3] = vw;
}

__global__ __launch_bounds__(256)
void loss_final(const float* __restrict__ part, float* __restrict__ out) {
    __shared__ float s[256];
    float acc = 0.f;
    for (int i = threadIdx.x; i < NLEV * 2048; i += 256) acc += part[i];
    s[threadIdx.x] = acc;
    __syncthreads();
    for (int st = 128; st; st >>= 1) {
        if (threadIdx.x < st) s[threadIdx.x] += s[threadIdx.x + st];
        __syncthreads();
    }
    if (threadIdx.x == 0)
        out[0] = s[0] * (1.001f / (4.0f * (float)N_ROWS * (float)EDIM));
}

// ============================================================================
extern "C" void kernel_launch(void* const* d_in, const int* in_sizes, int n_in,
                              void* d_out, int out_size, void* d_ws, size_t ws_size,
                              hipStream_t stream) {
    const float* x  = (const float*)d_in[0];
    const float* ew[4] = {(const float*)d_in[1], (const float*)d_in[3],
                          (const float*)d_in[5], (const float*)d_in[7]};
    const float* eb[4] = {(const float*)d_in[2], (const float*)d_in[4],
                          (const float*)d_in[6], (const float*)d_in[8]};
    const float* dw[4] = {(const float*)d_in[9],  (const float*)d_in[11],
                          (const float*)d_in[13], (const float*)d_in[15]};
    const float* db[4] = {(const float*)d_in[10], (const float*)d_in[12],
                          (const float*)d_in[14], (const float*)d_in[16]};
    const float* cbs = (const float*)d_in[17];

    float* out = (float*)d_out;
    const long LOSS_OFF = (long)N_ROWS * 768;
    const long IDX_OFF  = LOSS_OFF + 1;
    const long XQ_OFF   = IDX_OFF + (long)N_ROWS * 4;

    const int encK[4] = {768, 2048, 1024, 512}, encM[4] = {2048, 1024, 512, 128};
    const int decK[4] = {128, 512, 1024, 2048}, decM[4] = {512, 1024, 2048, 768};

    float* wsf = (float*)d_ws;
    long o32 = 0;
    float* zf    = wsf + o32; o32 += (long)N_ROWS * EDIM;
    float* res   = wsf + o32; o32 += (long)N_ROWS * EDIM;
    float* lossp = wsf + o32; o32 += NLEV * 2048;
    o32 = (o32 + 7) & ~7L;

    _Float16* wsh = (_Float16*)(wsf + o32);
    long oh = 0;
    _Float16* xqh = wsh + oh; oh += (long)N_ROWS * EDIM;
    _Float16 *ewh[4], *ewl[4], *dwh[4], *dwl[4];
    for (int j = 0; j < 4; ++j) {
        long n = (long)encK[j] * encM[j];
        ewh[j] = wsh + oh; oh += n;
        ewl[j] = wsh + oh; oh += n;
    }
    for (int j = 0; j < 4; ++j) {
        long n = (long)decK[j] * decM[j];
        dwh[j] = wsh + oh; oh += n;
        dwl[j] = wsh + oh; oh += n;
    }
    _Float16* a0h = wsh + oh; oh += (long)N_ROWS * 512;
    _Float16* a0l = wsh + oh; oh += (long)N_ROWS * 512;
    const long fixed_h = oh;

    long R = 16384;
    while (R > 2048) {
        size_t need = (size_t)o32 * 4 + (size_t)(fixed_h + R * (1536 + 4096 + 2048)) * 2;
        if (need <= ws_size) break;
        R >>= 1;
    }
    _Float16* xh  = wsh + oh; oh += R * 768;
    _Float16* xl  = wsh + oh; oh += R * 768;
    _Float16* a2h = wsh + oh; oh += R * 2048;
    _Float16* a2l = wsh + oh; oh += R * 2048;
    _Float16* a1h = wsh + oh; oh += R * 1024;
    _Float16* a1l = wsh + oh; oh += R * 1024;

    for (int j = 0; j < 4; ++j) {
        long n = (long)encK[j] * encM[j];
        splitWT<<<dim3((unsigned)((n + 255) / 256)), 256, 0, stream>>>(ew[j], ewh[j], ewl[j], encK[j], encM[j]);
        n = (long)decK[j] * decM[j];
        splitWT<<<dim3((unsigned)((n + 255) / 256)), 256, 0, stream>>>(dw[j], dwh[j], dwl[j], decK[j], decM[j]);
    }

    const int nchunks = N_ROWS / (int)R;
    const unsigned gy = (unsigned)(R / 128);
    const dim3 blk(256);

    // ---- encoder layers 0-2 (chunked), layer 3 full-N (same kernel) ----
    for (int c = 0; c < nchunks; ++c) {
        split_pair<<<dim3((unsigned)((R * 768 / 4 + 255) / 256)), 256, 0, stream>>>(
            x + (long)c * R * 768, xh, xl, R * 768 / 4);
        gemmQ<1,1,1><<<dim3(16, gy), blk, 0, stream>>>(xh,  xl,  ewh[0], ewl[0], eb[0],
                                                       nullptr, a2h, a2l, 768,  2048);
        gemmQ<1,1,1><<<dim3(8,  gy), blk, 0, stream>>>(a2h, a2l, ewh[1], ewl[1], eb[1],
                                                       nullptr, a1h, a1l, 2048, 1024);
        gemmQ<1,1,1><<<dim3(4,  gy), blk, 0, stream>>>(a1h, a1l, ewh[2], ewl[2], eb[2],
                                                       nullptr, a0h + (long)c * R * 512,
                                                       a0l + (long)c * R * 512, 1024, 512);
    }
    gemmQ<1,0,0><<<dim3(1, N_ROWS / 128), blk, 0, stream>>>(a0h, a0l, ewh[3], ewl[3], eb[3],
                                                            zf, nullptr, nullptr, 512, 128);

    // ---- residual VQ (fp32, exact) ----
    for (int l = 0; l < NLEV; ++l)
        vq_level<<<256, 512, 0, stream>>>(l == 0 ? zf : res, res, cbs, l, lossp, out + IDX_OFF);

    finalize_xq<<<(N_ROWS * EDIM / 4) / 256, 256, 0, stream>>>(zf, res, xqh, out + XQ_OFF);
    loss_final<<<1, 256, 0, stream>>>(lossp, out + LOSS_OFF);

    // ---- decoder (chunked, single-product fp16) ----
    for (int c = 0; c < nchunks; ++c) {
        gemmQ<0,2,1><<<dim3(4,  gy), blk, 0, stream>>>(xqh + (long)c * R * EDIM, nullptr,
                                                       dwh[0], nullptr, db[0],
                                                       nullptr, a0h, nullptr, 128,  512);
        gemmQ<0,2,1><<<dim3(8,  gy), blk, 0, stream>>>(a0h, nullptr, dwh[1], nullptr, db[1],
                                                       nullptr, a1h, nullptr, 512,  1024);
        gemmQ<0,2,1><<<dim3(16, gy), blk, 0, stream>>>(a1h, nullptr, dwh[2], nullptr, db[2],
                                                       nullptr, a2h, nullptr, 1024, 2048);
        gemmQ<0,0,0><<<dim3(6,  gy), blk, 0, stream>>>(a2h, nullptr, dwh[3], nullptr, db[3],
                                                       out + (long)c * R * 768, nullptr, nullptr, 2048, 768);
    }
}